// Round 19
// baseline (89.345 us; speedup 1.0000x reference)
//
#include <hip/hip_runtime.h>

#define K_CODES 1024
#define DIM 256
#define N_TOT 32768
#define LCAP 384

typedef _Float16 f16;
typedef _Float16 f16x8 __attribute__((ext_vector_type(8)));
typedef float f32x4 __attribute__((ext_vector_type(4)));

// Exact replica of numpy FLOAT_pairwise_sum for 128 contiguous squares (validated r3).
__device__ __forceinline__ float np_pw128_sq(const float* __restrict__ v) {
    float r[8];
    #pragma unroll
    for (int j = 0; j < 8; ++j) r[j] = __fmul_rn(v[j], v[j]);
    #pragma unroll
    for (int i = 1; i < 16; ++i)
        #pragma unroll
        for (int j = 0; j < 8; ++j)
            r[j] = __fadd_rn(r[j], __fmul_rn(v[8*i+j], v[8*i+j]));
    const float t01 = __fadd_rn(r[0], r[1]);
    const float t23 = __fadd_rn(r[2], r[3]);
    const float t45 = __fadd_rn(r[4], r[5]);
    const float t67 = __fadd_rn(r[6], r[7]);
    return __fadd_rn(__fadd_rn(t01, t23), __fadd_rn(t45, t67));
}

__global__ void vq_wnorm_kernel(const float* __restrict__ weight, float* __restrict__ wnorm) {
    int k = blockIdx.x * blockDim.x + threadIdx.x;
    if (k >= K_CODES) return;
    const float* wr = weight + (size_t)k * DIM;
    wnorm[k] = __fadd_rn(np_pw128_sq(wr), np_pw128_sq(wr + 128));
}

// f32 -> f16 -> bf8(e5m2) via RNE mantissa truncation (same exponent field).
__device__ __forceinline__ unsigned f32_to_bf8(float f) {
    _Float16 hf = (_Float16)f;
    unsigned short h;
    __builtin_memcpy(&h, &hf, 2);
    return ((unsigned)h + 0x7Fu + (((unsigned)h >> 8) & 1u)) >> 8;   // RNE, sign rides in bit 7
}

// W -> bf8 scaled by 1024 (exact pow2), stored TRANSPOSED by 8-dim units:
// Wht8[(unit*1024 + code)*8 .. +7] = bf8 of dims unit*8..unit*8+7 of `code`.
// A B-fragment load (lane fr->code, fg->unit plane) is 4x128B contiguous.
__global__ __launch_bounds__(256) void vq_convw_kernel(
    const float* __restrict__ weight, unsigned char* __restrict__ Wht8)
{
    const int g = blockIdx.x * 256 + threadIdx.x;   // 32768 threads: (unit, code)
    const int unit = g >> 10, code = g & 1023;
    const float4 v0 = *(const float4*)&weight[(size_t)code * DIM + unit * 8];
    const float4 v1 = *(const float4*)&weight[(size_t)code * DIM + unit * 8 + 4];
    uint2 o;
    o.x = f32_to_bf8(v0.x * 1024.f)        | (f32_to_bf8(v0.y * 1024.f) << 8)
        | (f32_to_bf8(v0.z * 1024.f) << 16) | (f32_to_bf8(v0.w * 1024.f) << 24);
    o.y = f32_to_bf8(v1.x * 1024.f)        | (f32_to_bf8(v1.y * 1024.f) << 8)
        | (f32_to_bf8(v1.z * 1024.f) << 16) | (f32_to_bf8(v1.w * 1024.f) << 24);
    *(uint2*)&Wht8[((size_t)unit * 1024 + code) * 8] = o;
}

// ======== fused: transpose + enc + bf8-MFMA argmin + gather + scatter =======
// Geometry/flow r18-verbatim (validated); screen dtype f16 -> bf8:
//  - halves codebook L2 bytes (512 -> 256 MB) -- the r18-diagnosed wall
//  - halves afr/bfr registers (r17 lesson: the 128-reg cliff is binding)
//  - screen-v error sigma ~9.4e-4 -> window 1e-2 (~10 sigma), LCAP 384;
//    bit-exact fp32 recheck unchanged => identical final numerics.
__global__ __launch_bounds__(256) __attribute__((amdgpu_waves_per_eu(4)))
void vq_fused_kernel(
    const float* __restrict__ x, const float* __restrict__ weight,
    const float* __restrict__ wnorm, const unsigned char* __restrict__ Wht8,
    float* __restrict__ enc_out, float* __restrict__ idx_out,
    float* __restrict__ qf_out, float* __restrict__ q_out)
{
    __shared__ __align__(16) float F[32][260];     // 33280 B (phase A + epilogue)
    __shared__ float wn[K_CODES];
    __shared__ unsigned rm[32];
    __shared__ unsigned long long rmEx[32];
    __shared__ unsigned list[LCAP];
    __shared__ unsigned lcount;

    const int tid = threadIdx.x;
    const int blk = blockIdx.x;        // b = blk>>5, h = blk&31
    const int b = blk >> 5, h = blk & 31;
    const long n0 = (long)blk * 32;
    const int wid = tid >> 6, lane = tid & 63;
    const int qw = wid;                // 4 waves = 4 code quarters (256 codes each)
    const int fr = lane & 15, fg = lane >> 4;

    if (tid < 32) { rm[tid] = 0xFFFFFFFFu; rmEx[tid] = 0xFFFFFFFFFFFFFFFFull; }
    if (tid == 0) lcount = 0;
    #pragma unroll
    for (int i = 0; i < 4; ++i) wn[tid + i * 256] = wnorm[tid + i * 256];

    // ---- Phase A: transpose x slice -> F (float4 loads), enc write, afr ----
    {
        const int wq = tid & 7, cb = tid >> 3;
        for (int c = cb; c < DIM; c += 32) {
            const float4 v = *(const float4*)&x[(((long)b * DIM + c) * 32 + h) * 32 + wq * 4];
            F[wq * 4 + 0][c] = v.x; F[wq * 4 + 1][c] = v.y;
            F[wq * 4 + 2][c] = v.z; F[wq * 4 + 3][c] = v.w;
        }
    }
    __syncthreads();
    {   // encoded_flat write (float4 coalesced)
        const int c4 = tid & 63, rg = tid >> 6;
        #pragma unroll
        for (int r0 = 0; r0 < 32; r0 += 4) {
            const int row = r0 + rg;
            *(float4*)&enc_out[(n0 + row) * DIM + c4 * 4] = *(const float4*)&F[row][c4 * 4];
        }
    }
    // afr extract: every wave holds all 32 rows (2 M-tiles x 8 K-steps), bf8-packed
    long afr[2][8];                    // 8 bf8 = 8 B per fragment (2 VGPR) -> 32 VGPR total
    #pragma unroll
    for (int mt = 0; mt < 2; ++mt)
        #pragma unroll
        for (int kk = 0; kk < 8; ++kk) {
            const float4 lo = *(const float4*)&F[mt * 16 + fr][kk * 32 + fg * 8];
            const float4 hi = *(const float4*)&F[mt * 16 + fr][kk * 32 + fg * 8 + 4];
            uint2 p;
            p.x = f32_to_bf8(lo.x)        | (f32_to_bf8(lo.y) << 8)
                | (f32_to_bf8(lo.z) << 16) | (f32_to_bf8(lo.w) << 24);
            p.y = f32_to_bf8(hi.x)        | (f32_to_bf8(hi.y) << 8)
                | (f32_to_bf8(hi.z) << 16) | (f32_to_bf8(hi.w) << 24);
            long v;
            __builtin_memcpy(&v, &p, 8);
            afr[mt][kk] = v;
        }
    __syncthreads();

    // ---- Phase B: barrier-free distance loop; bf8 B-frags from L2 ----
    unsigned s1[8], s2[8];                         // per-slot top-2 packed (v_q<<10 | k)
    #pragma unroll
    for (int i = 0; i < 8; ++i) { s1[i] = 0xFFFFFFFFu; s2[i] = 0xFFFFFFFFu; }

    const int lane_code = qw * 256 + fr;           // + ct*16 per step
    const unsigned char* const wbase = Wht8 + ((size_t)fg * 1024 + lane_code) * 8;

    #pragma unroll 2
    for (int ct = 0; ct < 16; ++ct) {
        const int code = qw * 256 + ct * 16 + fr;
        f32x4 acc0 = {0.f, 0.f, 0.f, 0.f}, acc1 = {0.f, 0.f, 0.f, 0.f};
        long bfr[8];
        #pragma unroll
        for (int kk = 0; kk < 8; ++kk)             // unit = kk*4+fg -> +kk*4*1024 rows of 8B
            bfr[kk] = *(const long*)(wbase + ((size_t)kk * 4096 + ct * 16) * 8);
        #pragma unroll
        for (int kk = 0; kk < 8; ++kk) {
            acc0 = __builtin_amdgcn_mfma_f32_16x16x32_bf8_bf8(afr[0][kk], bfr[kk], acc0, 0, 0, 0);
            acc1 = __builtin_amdgcn_mfma_f32_16x16x32_bf8_bf8(afr[1][kk], bfr[kk], acc1, 0, 0, 0);
        }
        const float wnk = wn[code];
        #pragma unroll
        for (int q = 0; q < 4; ++q) {
            {   // M-tile 0 (slot q): vp = wn - 2*dot (dot scaled /1024)
                const float vp = fmaf(acc0[q], -0.001953125f, wnk);
                const unsigned uq = (unsigned)fmaf(vp, 1048576.0f, 1048576.0f);
                const unsigned u = uq * 1024u + (unsigned)code;
                s2[q] = min(s2[q], max(s1[q], u));
                s1[q] = min(s1[q], u);
            }
            {   // M-tile 1 (slot 4+q)
                const float vp = fmaf(acc1[q], -0.001953125f, wnk);
                const unsigned uq = (unsigned)fmaf(vp, 1048576.0f, 1048576.0f);
                const unsigned u = uq * 1024u + (unsigned)code;
                s2[4 + q] = min(s2[4 + q], max(s1[4 + q], u));
                s1[4 + q] = min(s1[4 + q], u);
            }
        }
    }

    // ---- approximate per-row min (reduce fr lanes, merge 4 waves via atomics) ----
    #pragma unroll
    for (int sl = 0; sl < 8; ++sl) {
        unsigned bmin = s1[sl];
        bmin = min(bmin, (unsigned)__shfl_xor((int)bmin, 1));
        bmin = min(bmin, (unsigned)__shfl_xor((int)bmin, 2));
        bmin = min(bmin, (unsigned)__shfl_xor((int)bmin, 4));
        bmin = min(bmin, (unsigned)__shfl_xor((int)bmin, 8));
        if (fr == 0) {
            const int row = (sl >> 2) * 16 + fg * 4 + (sl & 3);
            atomicMin(&rm[row], bmin);
        }
    }
    __syncthreads();

    // ---- exact fp32 re-check (numpy-bit-exact r3 recipe; sE inline pairwise) ----
    auto exact_check = [&](int row, int k) {
        const float* ep = enc_out + (n0 + row) * DIM;
        const float* wp = weight + (long)k * DIM;
        float dot = 0.0f;
        float rr[8];
        #pragma unroll
        for (int j = 0; j < 8; ++j) rr[j] = 0.0f;
        #pragma unroll
        for (int dp = 0; dp < 16; ++dp) {
            {
                const float4 ev = *(const float4*)&ep[dp * 8];
                const float4 wv = *(const float4*)&wp[dp * 8];
                dot = __fmaf_rn(ev.x, wv.x, dot); dot = __fmaf_rn(ev.y, wv.y, dot);
                dot = __fmaf_rn(ev.z, wv.z, dot); dot = __fmaf_rn(ev.w, wv.w, dot);
                rr[0] = __fadd_rn(rr[0], __fmul_rn(ev.x, ev.x));
                rr[1] = __fadd_rn(rr[1], __fmul_rn(ev.y, ev.y));
                rr[2] = __fadd_rn(rr[2], __fmul_rn(ev.z, ev.z));
                rr[3] = __fadd_rn(rr[3], __fmul_rn(ev.w, ev.w));
            }
            {
                const float4 ev = *(const float4*)&ep[dp * 8 + 4];
                const float4 wv = *(const float4*)&wp[dp * 8 + 4];
                dot = __fmaf_rn(ev.x, wv.x, dot); dot = __fmaf_rn(ev.y, wv.y, dot);
                dot = __fmaf_rn(ev.z, wv.z, dot); dot = __fmaf_rn(ev.w, wv.w, dot);
                rr[4] = __fadd_rn(rr[4], __fmul_rn(ev.x, ev.x));
                rr[5] = __fadd_rn(rr[5], __fmul_rn(ev.y, ev.y));
                rr[6] = __fadd_rn(rr[6], __fmul_rn(ev.z, ev.z));
                rr[7] = __fadd_rn(rr[7], __fmul_rn(ev.w, ev.w));
            }
        }
        const float bA = __fadd_rn(__fadd_rn(__fadd_rn(rr[0], rr[1]), __fadd_rn(rr[2], rr[3])),
                                   __fadd_rn(__fadd_rn(rr[4], rr[5]), __fadd_rn(rr[6], rr[7])));
        #pragma unroll
        for (int j = 0; j < 8; ++j) rr[j] = 0.0f;
        #pragma unroll
        for (int dp = 0; dp < 16; ++dp) {
            {
                const float4 ev = *(const float4*)&ep[128 + dp * 8];
                const float4 wv = *(const float4*)&wp[128 + dp * 8];
                dot = __fmaf_rn(ev.x, wv.x, dot); dot = __fmaf_rn(ev.y, wv.y, dot);
                dot = __fmaf_rn(ev.z, wv.z, dot); dot = __fmaf_rn(ev.w, wv.w, dot);
                rr[0] = __fadd_rn(rr[0], __fmul_rn(ev.x, ev.x));
                rr[1] = __fadd_rn(rr[1], __fmul_rn(ev.y, ev.y));
                rr[2] = __fadd_rn(rr[2], __fmul_rn(ev.z, ev.z));
                rr[3] = __fadd_rn(rr[3], __fmul_rn(ev.w, ev.w));
            }
            {
                const float4 ev = *(const float4*)&ep[128 + dp * 8 + 4];
                const float4 wv = *(const float4*)&wp[128 + dp * 8 + 4];
                dot = __fmaf_rn(ev.x, wv.x, dot); dot = __fmaf_rn(ev.y, wv.y, dot);
                dot = __fmaf_rn(ev.z, wv.z, dot); dot = __fmaf_rn(ev.w, wv.w, dot);
                rr[4] = __fadd_rn(rr[4], __fmul_rn(ev.x, ev.x));
                rr[5] = __fadd_rn(rr[5], __fmul_rn(ev.y, ev.y));
                rr[6] = __fadd_rn(rr[6], __fmul_rn(ev.z, ev.z));
                rr[7] = __fadd_rn(rr[7], __fmul_rn(ev.w, ev.w));
            }
        }
        const float bB = __fadd_rn(__fadd_rn(__fadd_rn(rr[0], rr[1]), __fadd_rn(rr[2], rr[3])),
                                   __fadd_rn(__fadd_rn(rr[4], rr[5]), __fadd_rn(rr[6], rr[7])));
        const float sEr = __fadd_rn(bA, bB);
        const float vex = __fadd_rn(__fadd_rn(sEr, -__fmul_rn(2.0f, dot)), wn[k]);
        const unsigned long long pk =
            (((unsigned long long)__float_as_uint(vex)) << 10) | (unsigned long long)k;
        atomicMin(&rmEx[row], pk);
    };

    #pragma unroll
    for (int sl = 0; sl < 8; ++sl) {               // candidate compaction
        const int row = (sl >> 2) * 16 + fg * 4 + (sl & 3);
        const unsigned thr = (rm[row] >> 10) + 10000u; // ~1e-2 window (~10 sigma of bf8 screen)
        #pragma unroll
        for (int c = 0; c < 2; ++c) {
            const unsigned u = c ? s2[sl] : s1[sl];
            if ((u >> 10) <= thr) {
                const unsigned pos = atomicAdd(&lcount, 1u);
                if (pos < LCAP) list[pos] = ((unsigned)row << 10) | (u & 1023u);
                else exact_check(row, (int)(u & 1023u));
            }
        }
    }
    __syncthreads();
    {                                               // parallel exact pass
        const unsigned cnt = min(lcount, (unsigned)LCAP);
        for (unsigned t = tid; t < cnt; t += 256) {
            const unsigned ent = list[t];
            exact_check((int)(ent >> 10), (int)(ent & 1023u));
        }
    }
    __syncthreads();

    if (tid < 32) idx_out[n0 + tid] = (float)(unsigned)(rmEx[tid] & 1023ull);

    // ---- fused gather: codes -> qf_out (+ stash in F) + NCHW scatter ----
    {
        const int c4 = tid & 63, rg = tid >> 6;
        #pragma unroll
        for (int r0 = 0; r0 < 32; r0 += 4) {
            const int row = r0 + rg;
            const int k = (int)(unsigned)(rmEx[row] & 1023ull);
            const float4 v = *(const float4*)&weight[(long)k * DIM + c4 * 4];
            *(float4*)&qf_out[(n0 + row) * DIM + c4 * 4] = v;
            *(float4*)&F[row][c4 * 4] = v;
        }
    }
    __syncthreads();
    {
        const int w = tid & 31, c0 = tid >> 5;
        for (int c = c0; c < DIM; c += 8)
            q_out[(((long)b * DIM + c) * 32 + h) * 32 + w] = F[w][c];
    }
}

extern "C" void kernel_launch(void* const* d_in, const int* in_sizes, int n_in,
                              void* d_out, int out_size, void* d_ws, size_t ws_size,
                              hipStream_t stream)
{
    const float* x      = (const float*)d_in[0];   // [32,256,32,32]
    const float* weight = (const float*)d_in[1];   // [1024,256]

    float* out = (float*)d_out;
    float* enc = out;                                   // [32768,256]
    float* qf  = enc + (size_t)N_TOT * DIM;             // [32768,256]
    float* idx = qf  + (size_t)N_TOT * DIM;             // [32768] as float
    float* qo  = idx + N_TOT;                           // [32,256,32,32]

    float* wnorm        = (float*)d_ws;                 // 4 KB
    unsigned char* Wht8 = (unsigned char*)d_ws + 4096;  // 256 KB transposed bf8 codebook

    vq_wnorm_kernel<<<K_CODES / 256, 256, 0, stream>>>(weight, wnorm);
    vq_convw_kernel<<<128, 256, 0, stream>>>(weight, Wht8);
    vq_fused_kernel<<<1024, 256, 0, stream>>>(x, weight, wnorm, Wht8, enc, idx, qf, qo);
}

// Round 20
// 67.227 us; speedup vs baseline: 1.3290x; 1.3290x over previous
//
#include <hip/hip_runtime.h>

#define K_CODES 1024
#define DIM 256
#define N_TOT 32768
#define LCAP 192

typedef _Float16 f16;
typedef _Float16 f16x8 __attribute__((ext_vector_type(8)));
typedef float f32x4 __attribute__((ext_vector_type(4)));

// Exact replica of numpy FLOAT_pairwise_sum for 128 contiguous squares (validated r3).
__device__ __forceinline__ float np_pw128_sq(const float* __restrict__ v) {
    float r[8];
    #pragma unroll
    for (int j = 0; j < 8; ++j) r[j] = __fmul_rn(v[j], v[j]);
    #pragma unroll
    for (int i = 1; i < 16; ++i)
        #pragma unroll
        for (int j = 0; j < 8; ++j)
            r[j] = __fadd_rn(r[j], __fmul_rn(v[8*i+j], v[8*i+j]));
    const float t01 = __fadd_rn(r[0], r[1]);
    const float t23 = __fadd_rn(r[2], r[3]);
    const float t45 = __fadd_rn(r[4], r[5]);
    const float t67 = __fadd_rn(r[6], r[7]);
    return __fadd_rn(__fadd_rn(t01, t23), __fadd_rn(t45, t67));
}

// Merged prep: W -> f16 transposed codebook (all threads) + wnorm (threads 0-7
// of each of the 128 blocks handle one code row each: 128*8 = 1024).
// Wht[(unit*1024 + code)*8 .. +7] = f16(1024*w) of dims unit*8.. of `code`.
__global__ __launch_bounds__(256) void vq_prep_kernel(
    const float* __restrict__ weight, f16* __restrict__ Wht,
    float* __restrict__ wnorm)
{
    const int g = blockIdx.x * 256 + threadIdx.x;   // 32768 threads: (unit, code)
    const int unit = g >> 10, code = g & 1023;
    const float4 v0 = *(const float4*)&weight[(size_t)code * DIM + unit * 8];
    const float4 v1 = *(const float4*)&weight[(size_t)code * DIM + unit * 8 + 4];
    f16x8 o;
    o[0]=(f16)(v0.x*1024.f); o[1]=(f16)(v0.y*1024.f); o[2]=(f16)(v0.z*1024.f); o[3]=(f16)(v0.w*1024.f);
    o[4]=(f16)(v1.x*1024.f); o[5]=(f16)(v1.y*1024.f); o[6]=(f16)(v1.z*1024.f); o[7]=(f16)(v1.w*1024.f);
    *(f16x8*)&Wht[((size_t)unit * 1024 + code) * 8] = o;

    if (threadIdx.x < 8) {                          // numpy-pairwise ||w_k||^2
        const int k = blockIdx.x * 8 + threadIdx.x;
        const float* wr = weight + (size_t)k * DIM;
        wnorm[k] = __fadd_rn(np_pw128_sq(wr), np_pw128_sq(wr + 128));
    }
}

// ======== fused: transpose + enc + MFMA argmin + gather + scatter ===========
// r18-VERBATIM (validated 75.5us total, no spill). r17 lesson: any added live
// state in Phase B blows the 128-reg cap -> 800MB spill, 6x regression.
// r19 lesson: bf8 screen (half bytes, same inst count) = regression -> Phase B
// is cycle-bound, not byte-bound. Do not touch Phase B.
__global__ __launch_bounds__(256) __attribute__((amdgpu_waves_per_eu(4)))
void vq_fused_kernel(
    const float* __restrict__ x, const float* __restrict__ weight,
    const float* __restrict__ wnorm, const f16* __restrict__ Wht,
    float* __restrict__ enc_out, float* __restrict__ idx_out,
    float* __restrict__ qf_out, float* __restrict__ q_out)
{
    __shared__ __align__(16) float F[32][260];     // 33280 B (phase A + epilogue)
    __shared__ float wn[K_CODES];
    __shared__ unsigned rm[32];
    __shared__ unsigned long long rmEx[32];
    __shared__ unsigned list[LCAP];
    __shared__ unsigned lcount;

    const int tid = threadIdx.x;
    const int blk = blockIdx.x;        // b = blk>>5, h = blk&31
    const int b = blk >> 5, h = blk & 31;
    const long n0 = (long)blk * 32;
    const int wid = tid >> 6, lane = tid & 63;
    const int qw = wid;                // 4 waves = 4 code quarters (256 codes each)
    const int fr = lane & 15, fg = lane >> 4;

    if (tid < 32) { rm[tid] = 0xFFFFFFFFu; rmEx[tid] = 0xFFFFFFFFFFFFFFFFull; }
    if (tid == 0) lcount = 0;
    #pragma unroll
    for (int i = 0; i < 4; ++i) wn[tid + i * 256] = wnorm[tid + i * 256];

    // ---- Phase A: transpose x slice -> F (float4 loads), enc write, afr ----
    {
        const int wq = tid & 7, cb = tid >> 3;
        for (int c = cb; c < DIM; c += 32) {
            const float4 v = *(const float4*)&x[(((long)b * DIM + c) * 32 + h) * 32 + wq * 4];
            F[wq * 4 + 0][c] = v.x; F[wq * 4 + 1][c] = v.y;
            F[wq * 4 + 2][c] = v.z; F[wq * 4 + 3][c] = v.w;
        }
    }
    __syncthreads();
    {   // encoded_flat write (float4 coalesced)
        const int c4 = tid & 63, rg = tid >> 6;
        #pragma unroll
        for (int r0 = 0; r0 < 32; r0 += 4) {
            const int row = r0 + rg;
            *(float4*)&enc_out[(n0 + row) * DIM + c4 * 4] = *(const float4*)&F[row][c4 * 4];
        }
    }
    // afr extract: every wave holds all 32 rows (2 M-tiles x 8 K-steps)
    f16x8 afr[2][8];
    #pragma unroll
    for (int mt = 0; mt < 2; ++mt)
        #pragma unroll
        for (int kk = 0; kk < 8; ++kk) {
            const float4 lo = *(const float4*)&F[mt * 16 + fr][kk * 32 + fg * 8];
            const float4 hi = *(const float4*)&F[mt * 16 + fr][kk * 32 + fg * 8 + 4];
            f16x8 a;
            a[0] = (f16)lo.x; a[1] = (f16)lo.y; a[2] = (f16)lo.z; a[3] = (f16)lo.w;
            a[4] = (f16)hi.x; a[5] = (f16)hi.y; a[6] = (f16)hi.z; a[7] = (f16)hi.w;
            afr[mt][kk] = a;
        }
    __syncthreads();

    // ---- Phase B: barrier-free distance loop; B-frags from L2 (transposed) ----
    unsigned s1[8], s2[8];                         // per-slot top-2 packed (v_q<<10 | k)
    #pragma unroll
    for (int i = 0; i < 8; ++i) { s1[i] = 0xFFFFFFFFu; s2[i] = 0xFFFFFFFFu; }

    const int lane_code = qw * 256 + fr;           // + ct*16 per step
    const f16* const wbase = Wht + ((size_t)fg * 1024 + lane_code) * 8;

    #pragma unroll 2
    for (int ct = 0; ct < 16; ++ct) {
        const int code = qw * 256 + ct * 16 + fr;
        f32x4 acc0 = {0.f, 0.f, 0.f, 0.f}, acc1 = {0.f, 0.f, 0.f, 0.f};
        f16x8 bfr[8];
        #pragma unroll
        for (int kk = 0; kk < 8; ++kk)             // unit = kk*4+fg -> +kk*4*1024 elems
            bfr[kk] = *(const f16x8*)(wbase + ((size_t)kk * 4096 + ct * 16) * 8);
        #pragma unroll
        for (int kk = 0; kk < 8; ++kk) {
            acc0 = __builtin_amdgcn_mfma_f32_16x16x32_f16(afr[0][kk], bfr[kk], acc0, 0, 0, 0);
            acc1 = __builtin_amdgcn_mfma_f32_16x16x32_f16(afr[1][kk], bfr[kk], acc1, 0, 0, 0);
        }
        const float wnk = wn[code];
        #pragma unroll
        for (int q = 0; q < 4; ++q) {
            {   // M-tile 0 (slot q): vp = wn - 2*dot (dot scaled /1024)
                const float vp = fmaf(acc0[q], -0.001953125f, wnk);
                const unsigned uq = (unsigned)fmaf(vp, 1048576.0f, 1048576.0f);
                const unsigned u = uq * 1024u + (unsigned)code;
                s2[q] = min(s2[q], max(s1[q], u));
                s1[q] = min(s1[q], u);
            }
            {   // M-tile 1 (slot 4+q)
                const float vp = fmaf(acc1[q], -0.001953125f, wnk);
                const unsigned uq = (unsigned)fmaf(vp, 1048576.0f, 1048576.0f);
                const unsigned u = uq * 1024u + (unsigned)code;
                s2[4 + q] = min(s2[4 + q], max(s1[4 + q], u));
                s1[4 + q] = min(s1[4 + q], u);
            }
        }
    }

    // ---- approximate per-row min (reduce fr lanes, merge 4 waves via atomics) ----
    #pragma unroll
    for (int sl = 0; sl < 8; ++sl) {
        unsigned bmin = s1[sl];
        bmin = min(bmin, (unsigned)__shfl_xor((int)bmin, 1));
        bmin = min(bmin, (unsigned)__shfl_xor((int)bmin, 2));
        bmin = min(bmin, (unsigned)__shfl_xor((int)bmin, 4));
        bmin = min(bmin, (unsigned)__shfl_xor((int)bmin, 8));
        if (fr == 0) {
            const int row = (sl >> 2) * 16 + fg * 4 + (sl & 3);
            atomicMin(&rm[row], bmin);
        }
    }
    __syncthreads();

    // ---- exact fp32 re-check (numpy-bit-exact r3 recipe; sE inline pairwise) ----
    auto exact_check = [&](int row, int k) {
        const float* ep = enc_out + (n0 + row) * DIM;
        const float* wp = weight + (long)k * DIM;
        float dot = 0.0f;
        float rr[8];
        #pragma unroll
        for (int j = 0; j < 8; ++j) rr[j] = 0.0f;
        #pragma unroll
        for (int dp = 0; dp < 16; ++dp) {
            {
                const float4 ev = *(const float4*)&ep[dp * 8];
                const float4 wv = *(const float4*)&wp[dp * 8];
                dot = __fmaf_rn(ev.x, wv.x, dot); dot = __fmaf_rn(ev.y, wv.y, dot);
                dot = __fmaf_rn(ev.z, wv.z, dot); dot = __fmaf_rn(ev.w, wv.w, dot);
                rr[0] = __fadd_rn(rr[0], __fmul_rn(ev.x, ev.x));
                rr[1] = __fadd_rn(rr[1], __fmul_rn(ev.y, ev.y));
                rr[2] = __fadd_rn(rr[2], __fmul_rn(ev.z, ev.z));
                rr[3] = __fadd_rn(rr[3], __fmul_rn(ev.w, ev.w));
            }
            {
                const float4 ev = *(const float4*)&ep[dp * 8 + 4];
                const float4 wv = *(const float4*)&wp[dp * 8 + 4];
                dot = __fmaf_rn(ev.x, wv.x, dot); dot = __fmaf_rn(ev.y, wv.y, dot);
                dot = __fmaf_rn(ev.z, wv.z, dot); dot = __fmaf_rn(ev.w, wv.w, dot);
                rr[4] = __fadd_rn(rr[4], __fmul_rn(ev.x, ev.x));
                rr[5] = __fadd_rn(rr[5], __fmul_rn(ev.y, ev.y));
                rr[6] = __fadd_rn(rr[6], __fmul_rn(ev.z, ev.z));
                rr[7] = __fadd_rn(rr[7], __fmul_rn(ev.w, ev.w));
            }
        }
        const float bA = __fadd_rn(__fadd_rn(__fadd_rn(rr[0], rr[1]), __fadd_rn(rr[2], rr[3])),
                                   __fadd_rn(__fadd_rn(rr[4], rr[5]), __fadd_rn(rr[6], rr[7])));
        #pragma unroll
        for (int j = 0; j < 8; ++j) rr[j] = 0.0f;
        #pragma unroll
        for (int dp = 0; dp < 16; ++dp) {
            {
                const float4 ev = *(const float4*)&ep[128 + dp * 8];
                const float4 wv = *(const float4*)&wp[128 + dp * 8];
                dot = __fmaf_rn(ev.x, wv.x, dot); dot = __fmaf_rn(ev.y, wv.y, dot);
                dot = __fmaf_rn(ev.z, wv.z, dot); dot = __fmaf_rn(ev.w, wv.w, dot);
                rr[0] = __fadd_rn(rr[0], __fmul_rn(ev.x, ev.x));
                rr[1] = __fadd_rn(rr[1], __fmul_rn(ev.y, ev.y));
                rr[2] = __fadd_rn(rr[2], __fmul_rn(ev.z, ev.z));
                rr[3] = __fadd_rn(rr[3], __fmul_rn(ev.w, ev.w));
            }
            {
                const float4 ev = *(const float4*)&ep[128 + dp * 8 + 4];
                const float4 wv = *(const float4*)&wp[128 + dp * 8 + 4];
                dot = __fmaf_rn(ev.x, wv.x, dot); dot = __fmaf_rn(ev.y, wv.y, dot);
                dot = __fmaf_rn(ev.z, wv.z, dot); dot = __fmaf_rn(ev.w, wv.w, dot);
                rr[4] = __fadd_rn(rr[4], __fmul_rn(ev.x, ev.x));
                rr[5] = __fadd_rn(rr[5], __fmul_rn(ev.y, ev.y));
                rr[6] = __fadd_rn(rr[6], __fmul_rn(ev.z, ev.z));
                rr[7] = __fadd_rn(rr[7], __fmul_rn(ev.w, ev.w));
            }
        }
        const float bB = __fadd_rn(__fadd_rn(__fadd_rn(rr[0], rr[1]), __fadd_rn(rr[2], rr[3])),
                                   __fadd_rn(__fadd_rn(rr[4], rr[5]), __fadd_rn(rr[6], rr[7])));
        const float sEr = __fadd_rn(bA, bB);
        const float vex = __fadd_rn(__fadd_rn(sEr, -__fmul_rn(2.0f, dot)), wn[k]);
        const unsigned long long pk =
            (((unsigned long long)__float_as_uint(vex)) << 10) | (unsigned long long)k;
        atomicMin(&rmEx[row], pk);
    };

    #pragma unroll
    for (int sl = 0; sl < 8; ++sl) {               // candidate compaction
        const int row = (sl >> 2) * 16 + fg * 4 + (sl & 3);
        const unsigned thr = (rm[row] >> 10) + 1000u;  // ~9.5e-4 window
        #pragma unroll
        for (int c = 0; c < 2; ++c) {
            const unsigned u = c ? s2[sl] : s1[sl];
            if ((u >> 10) <= thr) {
                const unsigned pos = atomicAdd(&lcount, 1u);
                if (pos < LCAP) list[pos] = ((unsigned)row << 10) | (u & 1023u);
                else exact_check(row, (int)(u & 1023u));
            }
        }
    }
    __syncthreads();
    {                                               // parallel exact pass
        const unsigned cnt = min(lcount, (unsigned)LCAP);
        for (unsigned t = tid; t < cnt; t += 256) {
            const unsigned ent = list[t];
            exact_check((int)(ent >> 10), (int)(ent & 1023u));
        }
    }
    __syncthreads();

    if (tid < 32) idx_out[n0 + tid] = (float)(unsigned)(rmEx[tid] & 1023ull);

    // ---- fused gather: codes -> qf_out (+ stash in F) + NCHW scatter ----
    {
        const int c4 = tid & 63, rg = tid >> 6;
        #pragma unroll
        for (int r0 = 0; r0 < 32; r0 += 4) {
            const int row = r0 + rg;
            const int k = (int)(unsigned)(rmEx[row] & 1023ull);
            const float4 v = *(const float4*)&weight[(long)k * DIM + c4 * 4];
            *(float4*)&qf_out[(n0 + row) * DIM + c4 * 4] = v;
            *(float4*)&F[row][c4 * 4] = v;
        }
    }
    __syncthreads();
    {
        const int w = tid & 31, c0 = tid >> 5;
        for (int c = c0; c < DIM; c += 8)
            q_out[(((long)b * DIM + c) * 32 + h) * 32 + w] = F[w][c];
    }
}

extern "C" void kernel_launch(void* const* d_in, const int* in_sizes, int n_in,
                              void* d_out, int out_size, void* d_ws, size_t ws_size,
                              hipStream_t stream)
{
    const float* x      = (const float*)d_in[0];   // [32,256,32,32]
    const float* weight = (const float*)d_in[1];   // [1024,256]

    float* out = (float*)d_out;
    float* enc = out;                                   // [32768,256]
    float* qf  = enc + (size_t)N_TOT * DIM;             // [32768,256]
    float* idx = qf  + (size_t)N_TOT * DIM;             // [32768] as float
    float* qo  = idx + N_TOT;                           // [32,256,32,32]

    float* wnorm = (float*)d_ws;                        // 4 KB
    f16*   Wht   = (f16*)((char*)d_ws + 4096);          // 512 KB transposed f16 codebook

    vq_prep_kernel<<<128, 256, 0, stream>>>(weight, Wht, wnorm);
    vq_fused_kernel<<<1024, 256, 0, stream>>>(x, weight, wnorm, Wht, enc, idx, qf, qo);
}